// Round 1
// baseline (121.914 us; speedup 1.0000x reference)
//
#include <hip/hip_runtime.h>

#define B_ 8
#define C_ 19
#define H_ 512
#define W_ 512
#define HW_ (H_*W_)
#define N_ (B_*HW_)
#define K_RANK 100000
#define NBINS 2048
#define RED_BLOCKS 256

struct SelState { unsigned prefix; unsigned krem; float threshold; };

// ---------------- init: zero histograms + selection state ----------------
__global__ __launch_bounds__(256) void init_kernel(unsigned* __restrict__ hists,
                                                   SelState* __restrict__ st) {
    int i = blockIdx.x * blockDim.x + threadIdx.x;
    if (i < 3 * NBINS) hists[i] = 0u;
    if (i == 0) { st->prefix = 0u; st->krem = (unsigned)K_RANK; st->threshold = 0.7f; }
}

// ---------------- main: per-pixel CE loss + target-class prob ----------------
__global__ __launch_bounds__(256) void main_kernel(const float* __restrict__ logits,
                                                   const float* __restrict__ target,
                                                   float* __restrict__ pred,
                                                   float* __restrict__ lossv) {
    int n = blockIdx.x * blockDim.x + threadIdx.x;
    if (n >= N_) return;
    int b  = n >> 18;            // n / HW_
    int hw = n & (HW_ - 1);
    size_t base = (size_t)b * (size_t)(C_ * HW_) + (size_t)hw;
    const float* lp = logits + base;
    const float* tp = target + base;

    float l[C_];
    float m = -3.4e38f;
#pragma unroll
    for (int c = 0; c < C_; ++c) {
        l[c] = lp[(size_t)c * HW_];
        m = fmaxf(m, l[c]);
    }
    float s = 0.f, te = 0.f, tl = 0.f, ts = 0.f;
#pragma unroll
    for (int c = 0; c < C_; ++c) {
        float e = __expf(l[c] - m);
        s += e;
        float t = tp[(size_t)c * HW_];
        te += t * e;
        tl += t * l[c];
        ts += t;
    }
    float logs = __logf(s);
    lossv[n] = ts * (m + logs) - tl;   // == -(sum_c t_c * log_softmax_c)
    pred[n]  = te / s;                 // == sum_c t_c * softmax_c
}

// ---------------- radix-select histogram passes ----------------
template <int PASS>
__global__ __launch_bounds__(256) void hist_kernel(const float* __restrict__ pred,
                                                   unsigned* __restrict__ hist,
                                                   const SelState* __restrict__ st) {
    __shared__ unsigned lh[NBINS];
    for (int i = threadIdx.x; i < NBINS; i += blockDim.x) lh[i] = 0u;
    __syncthreads();
    unsigned prefix = st->prefix;
    int stride = gridDim.x * blockDim.x;
    for (int n = blockIdx.x * blockDim.x + threadIdx.x; n < N_; n += stride) {
        unsigned u = __float_as_uint(pred[n]);   // pred >= 0 -> uint order == float order
        if (PASS == 0) {
            atomicAdd(&lh[u >> 21], 1u);
        } else if (PASS == 1) {
            if ((u & 0xFFE00000u) == prefix) atomicAdd(&lh[(u >> 10) & 0x7FFu], 1u);
        } else {
            if ((u & 0xFFFFFC00u) == prefix) atomicAdd(&lh[u & 0x3FFu], 1u);
        }
    }
    __syncthreads();
    for (int i = threadIdx.x; i < NBINS; i += blockDim.x) {
        unsigned v = lh[i];
        if (v) atomicAdd(&hist[i], v);
    }
}

// ---------------- radix-select scan: find bin containing rank krem ----------------
template <int PASS>
__global__ __launch_bounds__(256) void scan_kernel(const unsigned* __restrict__ hist,
                                                   SelState* __restrict__ st) {
    __shared__ unsigned ssum[256];
    int t = threadIdx.x;
    unsigned k = st->krem;                     // all threads read BEFORE any write (syncs below)
    unsigned local[8];
    unsigned lsum = 0;
#pragma unroll
    for (int i = 0; i < 8; ++i) { local[i] = hist[t * 8 + i]; lsum += local[i]; }
    ssum[t] = lsum;
    __syncthreads();
    unsigned val = lsum;
    for (int off = 1; off < 256; off <<= 1) {   // Hillis-Steele inclusive scan
        unsigned other = (t >= off) ? ssum[t - off] : 0u;
        __syncthreads();
        val += other;
        ssum[t] = val;
        __syncthreads();
    }
    unsigned c = val - lsum;                    // exclusive prefix of this thread's 8 bins
#pragma unroll
    for (int i = 0; i < 8; ++i) {
        if (k >= c && k < c + local[i]) {       // exactly one (t,i) matches
            unsigned bin = (unsigned)(t * 8 + i);
            if (PASS == 0) { st->prefix = bin << 21; st->krem = k - c; }
            else if (PASS == 1) { st->prefix |= bin << 10; st->krem = k - c; }
            else {
                unsigned full = st->prefix | bin;
                st->threshold = fmaxf(__uint_as_float(full), 0.7f);
            }
        }
        c += local[i];
    }
}

// ---------------- masked reduction (deterministic, two stage) ----------------
__global__ __launch_bounds__(256) void reduce_kernel(const float* __restrict__ pred,
                                                     const float* __restrict__ lossv,
                                                     const SelState* __restrict__ st,
                                                     double* __restrict__ partials) {
    float thr = st->threshold;
    double sl = 0.0, sm = 0.0;
    int stride = gridDim.x * blockDim.x;
    for (int n = blockIdx.x * blockDim.x + threadIdx.x; n < N_; n += stride) {
        if (pred[n] < thr) { sl += (double)lossv[n]; sm += 1.0; }
    }
    __shared__ double s1[256], s2[256];
    int t = threadIdx.x;
    s1[t] = sl; s2[t] = sm;
    __syncthreads();
    for (int off = 128; off > 0; off >>= 1) {
        if (t < off) { s1[t] += s1[t + off]; s2[t] += s2[t + off]; }
        __syncthreads();
    }
    if (t == 0) { partials[2 * blockIdx.x] = s1[0]; partials[2 * blockIdx.x + 1] = s2[0]; }
}

__global__ __launch_bounds__(256) void final_kernel(const double* __restrict__ partials,
                                                    float* __restrict__ out) {
    __shared__ double s1[256], s2[256];
    int t = threadIdx.x;                        // RED_BLOCKS == 256 partial pairs
    s1[t] = partials[2 * t];
    s2[t] = partials[2 * t + 1];
    __syncthreads();
    for (int off = 128; off > 0; off >>= 1) {
        if (t < off) { s1[t] += s1[t + off]; s2[t] += s2[t + off]; }
        __syncthreads();
    }
    if (t == 0) out[0] = (float)(s1[0] / fmax(s2[0], 1.0));
}

extern "C" void kernel_launch(void* const* d_in, const int* in_sizes, int n_in,
                              void* d_out, int out_size, void* d_ws, size_t ws_size,
                              hipStream_t stream) {
    const float* logits = (const float*)d_in[0];
    const float* target = (const float*)d_in[1];
    float* out = (float*)d_out;

    char* ws = (char*)d_ws;
    float*    pred     = (float*)ws;                                   // 8 MiB
    float*    lossv    = (float*)(ws + (size_t)N_ * 4);                // 8 MiB
    unsigned* hists    = (unsigned*)(ws + (size_t)N_ * 8);             // 3*8 KiB
    SelState* st       = (SelState*)(ws + (size_t)N_ * 8 + 3 * NBINS * 4);
    double*   partials = (double*)(ws + (size_t)N_ * 8 + 3 * NBINS * 4 + 64);

    unsigned* h0 = hists;
    unsigned* h1 = hists + NBINS;
    unsigned* h2 = hists + 2 * NBINS;

    init_kernel<<<(3 * NBINS + 255) / 256, 256, 0, stream>>>(hists, st);
    main_kernel<<<N_ / 256, 256, 0, stream>>>(logits, target, pred, lossv);
    hist_kernel<0><<<256, 256, 0, stream>>>(pred, h0, st);
    scan_kernel<0><<<1, 256, 0, stream>>>(h0, st);
    hist_kernel<1><<<256, 256, 0, stream>>>(pred, h1, st);
    scan_kernel<1><<<1, 256, 0, stream>>>(h1, st);
    hist_kernel<2><<<256, 256, 0, stream>>>(pred, h2, st);
    scan_kernel<2><<<1, 256, 0, stream>>>(h2, st);
    reduce_kernel<<<RED_BLOCKS, 256, 0, stream>>>(pred, lossv, st, partials);
    final_kernel<<<1, 256, 0, stream>>>(partials, out);
}

// Round 2
// 97.076 us; speedup vs baseline: 1.2559x; 1.2559x over previous
//
#include <hip/hip_runtime.h>

#define B_ 8
#define C_ 19
#define H_ 512
#define W_ 512
#define HW_ (H_*W_)
#define N_ (B_*HW_)
#define HW4 (HW_/4)          /* 65536 float4 per channel-plane */
#define N4 (N_/4)            /* 524288 */
#define CH4 (C_*HW4)
#define K_RANK 100000
#define NBINS 2048
#define RED_BLOCKS 256

struct SelState { unsigned prefix; unsigned krem; float threshold; };

// ---------------- init: zero histograms + selection state ----------------
__global__ __launch_bounds__(256) void init_kernel(unsigned* __restrict__ hists,
                                                   SelState* __restrict__ st) {
    int i = blockIdx.x * blockDim.x + threadIdx.x;
    if (i < 3 * NBINS) hists[i] = 0u;
    if (i == 0) { st->prefix = 0u; st->krem = (unsigned)K_RANK; st->threshold = 0.7f; }
}

// ---------------- main: per-pixel CE loss + target prob, 4 pixels/thread ----------------
// Also fuses radix-select histogram pass 0 (11 high bits of pred).
__global__ __launch_bounds__(256) void main_kernel(const float4* __restrict__ logits,
                                                   const float4* __restrict__ target,
                                                   float4* __restrict__ pred,
                                                   float4* __restrict__ lossv,
                                                   unsigned* __restrict__ h0) {
    __shared__ unsigned lh[NBINS];
    for (int i = threadIdx.x; i < NBINS; i += 256) lh[i] = 0u;
    __syncthreads();

    int n4 = blockIdx.x * 256 + threadIdx.x;       // grid sized exactly N4/256
    int b   = n4 >> 16;                            // n4 / HW4
    int hw4 = n4 & (HW4 - 1);
    size_t base = (size_t)b * (size_t)CH4 + (size_t)hw4;
    const float4* lp = logits + base;
    const float4* tp = target + base;

    float4 l[C_];
    float mx = -3.4e38f, my = -3.4e38f, mz = -3.4e38f, mw = -3.4e38f;
#pragma unroll
    for (int c = 0; c < C_; ++c) {
        float4 v = lp[(size_t)c * HW4];
        l[c] = v;
        mx = fmaxf(mx, v.x); my = fmaxf(my, v.y);
        mz = fmaxf(mz, v.z); mw = fmaxf(mw, v.w);
    }
    float sx = 0.f, sy = 0.f, sz = 0.f, sw = 0.f;
    float tex = 0.f, tey = 0.f, tez = 0.f, tew = 0.f;
    float tlx = 0.f, tly = 0.f, tlz = 0.f, tlw = 0.f;
    float tsx = 0.f, tsy = 0.f, tsz = 0.f, tsw = 0.f;
#pragma unroll
    for (int c = 0; c < C_; ++c) {
        float4 t = tp[(size_t)c * HW4];
        float ex = __expf(l[c].x - mx), ey = __expf(l[c].y - my);
        float ez = __expf(l[c].z - mz), ew = __expf(l[c].w - mw);
        sx += ex; sy += ey; sz += ez; sw += ew;
        tex += t.x * ex; tey += t.y * ey; tez += t.z * ez; tew += t.w * ew;
        tlx += t.x * l[c].x; tly += t.y * l[c].y; tlz += t.z * l[c].z; tlw += t.w * l[c].w;
        tsx += t.x; tsy += t.y; tsz += t.z; tsw += t.w;
    }
    float4 lo, pr;
    lo.x = tsx * (mx + __logf(sx)) - tlx;  pr.x = tex / sx;
    lo.y = tsy * (my + __logf(sy)) - tly;  pr.y = tey / sy;
    lo.z = tsz * (mz + __logf(sz)) - tlz;  pr.z = tez / sz;
    lo.w = tsw * (mw + __logf(sw)) - tlw;  pr.w = tew / sw;
    lossv[n4] = lo;
    pred[n4]  = pr;

    // fused histogram pass 0 (pred >= 0 so uint order == float order)
    atomicAdd(&lh[__float_as_uint(pr.x) >> 21], 1u);
    atomicAdd(&lh[__float_as_uint(pr.y) >> 21], 1u);
    atomicAdd(&lh[__float_as_uint(pr.z) >> 21], 1u);
    atomicAdd(&lh[__float_as_uint(pr.w) >> 21], 1u);
    __syncthreads();
    for (int i = threadIdx.x; i < NBINS; i += 256) {
        unsigned v = lh[i];
        if (v) atomicAdd(&h0[i], v);
    }
}

// ---------------- radix-select histogram passes 1,2 (float4 reads) ----------------
template <int PASS>
__global__ __launch_bounds__(256) void hist_kernel(const float4* __restrict__ pred,
                                                   unsigned* __restrict__ hist,
                                                   const SelState* __restrict__ st) {
    __shared__ unsigned lh[NBINS];
    for (int i = threadIdx.x; i < NBINS; i += blockDim.x) lh[i] = 0u;
    __syncthreads();
    unsigned prefix = st->prefix;
    int stride = gridDim.x * blockDim.x;
    for (int n = blockIdx.x * blockDim.x + threadIdx.x; n < N4; n += stride) {
        float4 p = pred[n];
        unsigned u0 = __float_as_uint(p.x), u1 = __float_as_uint(p.y);
        unsigned u2 = __float_as_uint(p.z), u3 = __float_as_uint(p.w);
        if (PASS == 1) {
            if ((u0 & 0xFFE00000u) == prefix) atomicAdd(&lh[(u0 >> 10) & 0x7FFu], 1u);
            if ((u1 & 0xFFE00000u) == prefix) atomicAdd(&lh[(u1 >> 10) & 0x7FFu], 1u);
            if ((u2 & 0xFFE00000u) == prefix) atomicAdd(&lh[(u2 >> 10) & 0x7FFu], 1u);
            if ((u3 & 0xFFE00000u) == prefix) atomicAdd(&lh[(u3 >> 10) & 0x7FFu], 1u);
        } else {
            if ((u0 & 0xFFFFFC00u) == prefix) atomicAdd(&lh[u0 & 0x3FFu], 1u);
            if ((u1 & 0xFFFFFC00u) == prefix) atomicAdd(&lh[u1 & 0x3FFu], 1u);
            if ((u2 & 0xFFFFFC00u) == prefix) atomicAdd(&lh[u2 & 0x3FFu], 1u);
            if ((u3 & 0xFFFFFC00u) == prefix) atomicAdd(&lh[u3 & 0x3FFu], 1u);
        }
    }
    __syncthreads();
    for (int i = threadIdx.x; i < NBINS; i += blockDim.x) {
        unsigned v = lh[i];
        if (v) atomicAdd(&hist[i], v);
    }
}

// ---------------- radix-select scan: find bin containing rank krem ----------------
template <int PASS>
__global__ __launch_bounds__(256) void scan_kernel(const unsigned* __restrict__ hist,
                                                   SelState* __restrict__ st) {
    __shared__ unsigned ssum[256];
    int t = threadIdx.x;
    unsigned k = st->krem;
    unsigned local[8];
    unsigned lsum = 0;
#pragma unroll
    for (int i = 0; i < 8; ++i) { local[i] = hist[t * 8 + i]; lsum += local[i]; }
    ssum[t] = lsum;
    __syncthreads();
    unsigned val = lsum;
    for (int off = 1; off < 256; off <<= 1) {   // Hillis-Steele inclusive scan
        unsigned other = (t >= off) ? ssum[t - off] : 0u;
        __syncthreads();
        val += other;
        ssum[t] = val;
        __syncthreads();
    }
    unsigned c = val - lsum;                    // exclusive prefix of this thread's 8 bins
#pragma unroll
    for (int i = 0; i < 8; ++i) {
        if (k >= c && k < c + local[i]) {       // exactly one (t,i) matches
            unsigned bin = (unsigned)(t * 8 + i);
            if (PASS == 0) { st->prefix = bin << 21; st->krem = k - c; }
            else if (PASS == 1) { st->prefix |= bin << 10; st->krem = k - c; }
            else {
                unsigned full = st->prefix | bin;
                st->threshold = fmaxf(__uint_as_float(full), 0.7f);
            }
        }
        c += local[i];
    }
}

// ---------------- masked reduction (deterministic, two stage) ----------------
__global__ __launch_bounds__(256) void reduce_kernel(const float4* __restrict__ pred,
                                                     const float4* __restrict__ lossv,
                                                     const SelState* __restrict__ st,
                                                     double* __restrict__ partials) {
    float thr = st->threshold;
    double sl = 0.0, sm = 0.0;
    int stride = gridDim.x * blockDim.x;
    for (int n = blockIdx.x * blockDim.x + threadIdx.x; n < N4; n += stride) {
        float4 p = pred[n];
        float4 lo = lossv[n];
        if (p.x < thr) { sl += (double)lo.x; sm += 1.0; }
        if (p.y < thr) { sl += (double)lo.y; sm += 1.0; }
        if (p.z < thr) { sl += (double)lo.z; sm += 1.0; }
        if (p.w < thr) { sl += (double)lo.w; sm += 1.0; }
    }
    __shared__ double s1[256], s2[256];
    int t = threadIdx.x;
    s1[t] = sl; s2[t] = sm;
    __syncthreads();
    for (int off = 128; off > 0; off >>= 1) {
        if (t < off) { s1[t] += s1[t + off]; s2[t] += s2[t + off]; }
        __syncthreads();
    }
    if (t == 0) { partials[2 * blockIdx.x] = s1[0]; partials[2 * blockIdx.x + 1] = s2[0]; }
}

__global__ __launch_bounds__(256) void final_kernel(const double* __restrict__ partials,
                                                    float* __restrict__ out) {
    __shared__ double s1[256], s2[256];
    int t = threadIdx.x;                        // RED_BLOCKS == 256 partial pairs
    s1[t] = partials[2 * t];
    s2[t] = partials[2 * t + 1];
    __syncthreads();
    for (int off = 128; off > 0; off >>= 1) {
        if (t < off) { s1[t] += s1[t + off]; s2[t] += s2[t + off]; }
        __syncthreads();
    }
    if (t == 0) out[0] = (float)(s1[0] / fmax(s2[0], 1.0));
}

extern "C" void kernel_launch(void* const* d_in, const int* in_sizes, int n_in,
                              void* d_out, int out_size, void* d_ws, size_t ws_size,
                              hipStream_t stream) {
    const float4* logits = (const float4*)d_in[0];
    const float4* target = (const float4*)d_in[1];
    float* out = (float*)d_out;

    char* ws = (char*)d_ws;
    float4*   pred     = (float4*)ws;                                  // 8 MiB
    float4*   lossv    = (float4*)(ws + (size_t)N_ * 4);               // 8 MiB
    unsigned* hists    = (unsigned*)(ws + (size_t)N_ * 8);             // 3*8 KiB
    SelState* st       = (SelState*)(ws + (size_t)N_ * 8 + 3 * NBINS * 4);
    double*   partials = (double*)(ws + (size_t)N_ * 8 + 3 * NBINS * 4 + 64);

    unsigned* h0 = hists;
    unsigned* h1 = hists + NBINS;
    unsigned* h2 = hists + 2 * NBINS;

    init_kernel<<<(3 * NBINS + 255) / 256, 256, 0, stream>>>(hists, st);
    main_kernel<<<N4 / 256, 256, 0, stream>>>(logits, target, pred, lossv, h0);
    scan_kernel<0><<<1, 256, 0, stream>>>(h0, st);
    hist_kernel<1><<<256, 256, 0, stream>>>(pred, h1, st);
    scan_kernel<1><<<1, 256, 0, stream>>>(h1, st);
    hist_kernel<2><<<256, 256, 0, stream>>>(pred, h2, st);
    scan_kernel<2><<<1, 256, 0, stream>>>(h2, st);
    reduce_kernel<<<RED_BLOCKS, 256, 0, stream>>>(pred, lossv, st, partials);
    final_kernel<<<1, 256, 0, stream>>>(partials, out);
}